// Round 2
// baseline (176.328 us; speedup 1.0000x reference)
//
#include <hip/hip_runtime.h>
#include <hip/hip_cooperative_groups.h>

#define BATCH 8192
#define IN 128
#define OUT 128
#define NB 18
#define ROW (IN * NB)          // 2304
#define CF_ELEMS (OUT * ROW)   // 294912
#define MT 32                  // batch rows per block
#define NCHG 4                 // K-chunks per K-group (2 groups x 4 x 288 = 2304)
#define NBLK (BATCH / MT)      // 256 blocks (125KB LDS => 1 blk/CU, validated by coop launch)
#define CVT_PER_BLK (CF_ELEMS / 8 / NBLK)   // 144 uint4 converted per block

typedef short  bf16x8 __attribute__((ext_vector_type(8)));
typedef float  f32x16 __attribute__((ext_vector_type(16)));

static __device__ __forceinline__ unsigned short f2bf(float f) {
    union { float f; unsigned u; } v; v.f = f;
    unsigned r = v.u + 0x7fffu + ((v.u >> 16) & 1u);   // RNE
    return (unsigned short)(r >> 16);
}
static __device__ __forceinline__ bf16x8 as_bf16x8(uint4 v) {
    union { uint4 u; bf16x8 b; } x; x.u = v; return x.b;
}
static __device__ __forceinline__ float fast_tanh(float v) {
    float e = __expf(2.0f * v);
    return 1.0f - 2.0f * __builtin_amdgcn_rcpf(e + 1.0f);
}

// Fused cooperative kernel: per-block slice convert (fp32 [o][k] -> bf16 tiled
// [k>>3][o][k&7]), grid.sync(), then the proven MFMA pipeline (unchanged).
__global__ __launch_bounds__(512, 2) void kan_fused(const float* __restrict__ x,
                                                    const float* __restrict__ cf,
                                                    unsigned short* __restrict__ cfb2,
                                                    float* __restrict__ out) {
    // A-tile transposed: [group][3 bufs][granule 0..35][row*4 + dw]
    __shared__ unsigned sAT[2][3][36][128];   // 108 KB
    __shared__ float sbuf[MT][132];           // 16.9 KB x-stage (132%32=4 -> conflict-free)
    __shared__ float s_xsp[2][MT];

    const int t  = threadIdx.x;
    const int g  = t >> 8;          // K-group 0/1
    const int tg = t & 255;
    const int w4 = (t >> 6) & 3;    // N-slice
    const int l  = t & 63;
    const int b0 = blockIdx.x * MT;
    const int n0 = w4 << 5;
    const int ab = tg >> 3;         // A-build row 0..31
    const int iq = tg & 7;
    const int h  = l >> 5;          // k-octet half
    const int am = l & 31;

    // ---- conversion slice: this block converts 144 uint4 of cfb2 ----
    if (t < CVT_PER_BLK) {
        int idx = blockIdx.x * CVT_PER_BLK + t;
        int o  = idx & 127;
        int kb = idx >> 7;
        const float4* src = (const float4*)(cf + o * ROW + kb * 8);
        float4 a = src[0], b = src[1];
        uint4 pk;
        pk.x = (unsigned)f2bf(a.x) | ((unsigned)f2bf(a.y) << 16);
        pk.y = (unsigned)f2bf(a.z) | ((unsigned)f2bf(a.w) << 16);
        pk.z = (unsigned)f2bf(b.x) | ((unsigned)f2bf(b.y) << 16);
        pk.w = (unsigned)f2bf(b.z) | ((unsigned)f2bf(b.w) << 16);
        ((uint4*)cfb2)[idx] = pk;
    }

    // ---- stage x (coalesced float4, 16B-aligned: 132*4B = 33*16B) ----
    {
        const float4* xp = (const float4*)(x + b0 * IN);
        int i0 = t;
        *(float4*)&sbuf[i0 >> 5][(i0 & 31) << 2] = xp[i0];
        int i1 = t + 512;
        *(float4*)&sbuf[i1 >> 5][(i1 & 31) << 2] = xp[i1];
    }
    __syncthreads();

    f32x16 accA, accB;
    #pragma unroll
    for (int r = 0; r < 16; ++r) { accA[r] = 0.f; accB[r] = 0.f; }
    float xs = 0.f;

    const uint4* bbase = (const uint4*)cfb2;
    const int o = n0 + am;

    // ---- A-build for chunk c into buffer nb (LDS-only, safe pre-sync) ----
    auto build = [&](int c, int nb) {
        unsigned* tile = &sAT[g][nb][0][0];
        #pragma unroll
        for (int hh = 0; hh < 2; ++hh) {
            int il = iq + (hh << 3);
            int i  = (c << 4) + il;
            float xt = fast_tanh(sbuf[ab][i]);
            xs += xt;
            float s = (xt + 1.0f) * 7.5f;
            int m = (int)s; m = m < 0 ? 0 : (m > 14 ? 14 : m);
            float u = s - (float)m, om = 1.f - u, u2 = u * u;
            float w0 = (1.f / 6.f) * om * om * om;
            float w1 = (2.f / 3.f) - u2 * (1.f - 0.5f * u);
            float w2 = (1.f / 6.f) + 0.5f * (u + u2 - u2 * u);
            float w3 = (1.f / 6.f) * u * u2;
            unsigned lo = (unsigned)f2bf(w0) | ((unsigned)f2bf(w1) << 16);
            unsigned hi = (unsigned)f2bf(w2) | ((unsigned)f2bf(w3) << 16);
            int odd = m & 1;
            unsigned t0 = odd ? (lo << 16) : lo;
            unsigned t1 = odd ? ((hi << 16) | (lo >> 16)) : hi;
            unsigned t2 = odd ? (hi >> 16) : 0u;
            int dq = m >> 1;
            int d0 = il * 9;
            #pragma unroll
            for (int j = 0; j < 9; ++j) {
                int d = d0 + j;
                unsigned v = (j == dq) ? t0 : (j == dq + 1) ? t1
                           : (j == dq + 2) ? t2 : 0u;
                tile[((d >> 2) << 7) + (ab << 2) + (d & 3)] = v;   // 2-way max
            }
        }
    };

    build(g * NCHG, 0);     // prologue build hides grid-sync skew (no cfb2 access)

    // ---- grid barrier: all blocks' conversion slices written + visible ----
    __threadfence();                          // release: drain + L2 writeback
    cooperative_groups::this_grid().sync();   // runtime-validated co-residency
    __threadfence();                          // acquire: invalidate stale L1/XCD-L2

    #pragma unroll
    for (int cc = 0; cc < NCHG; ++cc) {
        const int c = g * NCHG + cc;
        // B fragments for chunk c (global, issued before build VALU hides them)
        uint4 B[18];
        #pragma unroll
        for (int s = 0; s < 18; ++s)
            B[s] = bbase[(c * 36 + 2 * s + h) * 128 + o];
        if (cc + 1 < NCHG) build(c + 1, (cc + 1) % 3);
        __syncthreads();    // buf cc%3 complete for all waves
        const unsigned* tb = &sAT[g][cc % 3][0][0];
        #pragma unroll
        for (int s = 0; s < 18; ++s) {
            uint4 av = *(const uint4*)(tb + (((2 * s + h) << 7) + (am << 2)));
            if (s & 1) accB = __builtin_amdgcn_mfma_f32_32x32x16_bf16(
                                  as_bf16x8(av), as_bf16x8(B[s]), accB, 0, 0, 0);
            else       accA = __builtin_amdgcn_mfma_f32_32x32x16_bf16(
                                  as_bf16x8(av), as_bf16x8(B[s]), accA, 0, 0, 0);
        }
    }

    #pragma unroll
    for (int r = 0; r < 16; ++r) accA[r] += accB[r];

    // ---- tanh partial sums: 8 consecutive lanes share (g, ab) ----
    xs += __shfl_down(xs, 4, 8);
    xs += __shfl_down(xs, 2, 8);
    xs += __shfl_down(xs, 1, 8);
    if (iq == 0) s_xsp[g][ab] = xs;

    // ---- K-group reduction via sbuf (x-stage dead) ----
    if (g == 1) {
        #pragma unroll
        for (int r = 0; r < 16; ++r) {
            int row = (r & 3) + ((r >> 2) << 3) + (h << 2);
            sbuf[row][n0 + am] = accA[r];
        }
    }
    __syncthreads();
    if (g == 0) {
        #pragma unroll
        for (int r = 0; r < 16; ++r) {
            int row = (r & 3) + ((r >> 2) << 3) + (h << 2);
            float v = accA[r] + sbuf[row][n0 + am] + s_xsp[0][row] + s_xsp[1][row];
            out[(b0 + row) * OUT + n0 + am] = v * (1.0f / 128.0f);
        }
    }
}

// ---------------- proven two-kernel path (fallback if coop launch fails) ----------------
// cf fp32 [o][k] -> cfb2 bf16 tiled [k>>3][o][k&7]
__global__ __launch_bounds__(256) void cvt_kernel(const float* __restrict__ cf,
                                                  unsigned short* __restrict__ cfb2) {
    int tid = blockIdx.x * 256 + threadIdx.x;
    int o  = tid & 127;
    int kb = tid >> 7;
    const float4* src = (const float4*)(cf + o * ROW + kb * 8);
    float4 a = src[0], b = src[1];
    uint4 pk;
    pk.x = (unsigned)f2bf(a.x) | ((unsigned)f2bf(a.y) << 16);
    pk.y = (unsigned)f2bf(a.z) | ((unsigned)f2bf(a.w) << 16);
    pk.z = (unsigned)f2bf(b.x) | ((unsigned)f2bf(b.y) << 16);
    pk.w = (unsigned)f2bf(b.z) | ((unsigned)f2bf(b.w) << 16);
    ((uint4*)cfb2)[tid] = pk;
}

__global__ __launch_bounds__(512, 2) void kan_mfma(const float* __restrict__ x,
                                                   const unsigned short* __restrict__ cfb2,
                                                   float* __restrict__ out) {
    __shared__ unsigned sAT[2][3][36][128];
    __shared__ float sbuf[MT][132];
    __shared__ float s_xsp[2][MT];

    const int t  = threadIdx.x;
    const int g  = t >> 8;
    const int tg = t & 255;
    const int w4 = (t >> 6) & 3;
    const int l  = t & 63;
    const int b0 = blockIdx.x * MT;
    const int n0 = w4 << 5;
    const int ab = tg >> 3;
    const int iq = tg & 7;
    const int h  = l >> 5;
    const int am = l & 31;

    {
        const float4* xp = (const float4*)(x + b0 * IN);
        int i0 = t;
        *(float4*)&sbuf[i0 >> 5][(i0 & 31) << 2] = xp[i0];
        int i1 = t + 512;
        *(float4*)&sbuf[i1 >> 5][(i1 & 31) << 2] = xp[i1];
    }
    __syncthreads();

    f32x16 accA, accB;
    #pragma unroll
    for (int r = 0; r < 16; ++r) { accA[r] = 0.f; accB[r] = 0.f; }
    float xs = 0.f;

    const uint4* bbase = (const uint4*)cfb2;
    const int o = n0 + am;

    auto build = [&](int c, int nb) {
        unsigned* tile = &sAT[g][nb][0][0];
        #pragma unroll
        for (int hh = 0; hh < 2; ++hh) {
            int il = iq + (hh << 3);
            int i  = (c << 4) + il;
            float xt = fast_tanh(sbuf[ab][i]);
            xs += xt;
            float s = (xt + 1.0f) * 7.5f;
            int m = (int)s; m = m < 0 ? 0 : (m > 14 ? 14 : m);
            float u = s - (float)m, om = 1.f - u, u2 = u * u;
            float w0 = (1.f / 6.f) * om * om * om;
            float w1 = (2.f / 3.f) - u2 * (1.f - 0.5f * u);
            float w2 = (1.f / 6.f) + 0.5f * (u + u2 - u2 * u);
            float w3 = (1.f / 6.f) * u * u2;
            unsigned lo = (unsigned)f2bf(w0) | ((unsigned)f2bf(w1) << 16);
            unsigned hi = (unsigned)f2bf(w2) | ((unsigned)f2bf(w3) << 16);
            int odd = m & 1;
            unsigned t0 = odd ? (lo << 16) : lo;
            unsigned t1 = odd ? ((hi << 16) | (lo >> 16)) : hi;
            unsigned t2 = odd ? (hi >> 16) : 0u;
            int dq = m >> 1;
            int d0 = il * 9;
            #pragma unroll
            for (int j = 0; j < 9; ++j) {
                int d = d0 + j;
                unsigned v = (j == dq) ? t0 : (j == dq + 1) ? t1
                           : (j == dq + 2) ? t2 : 0u;
                tile[((d >> 2) << 7) + (ab << 2) + (d & 3)] = v;
            }
        }
    };

    build(g * NCHG, 0);

    #pragma unroll
    for (int cc = 0; cc < NCHG; ++cc) {
        const int c = g * NCHG + cc;
        uint4 B[18];
        #pragma unroll
        for (int s = 0; s < 18; ++s)
            B[s] = bbase[(c * 36 + 2 * s + h) * 128 + o];
        if (cc + 1 < NCHG) build(c + 1, (cc + 1) % 3);
        __syncthreads();
        const unsigned* tb = &sAT[g][cc % 3][0][0];
        #pragma unroll
        for (int s = 0; s < 18; ++s) {
            uint4 av = *(const uint4*)(tb + (((2 * s + h) << 7) + (am << 2)));
            if (s & 1) accB = __builtin_amdgcn_mfma_f32_32x32x16_bf16(
                                  as_bf16x8(av), as_bf16x8(B[s]), accB, 0, 0, 0);
            else       accA = __builtin_amdgcn_mfma_f32_32x32x16_bf16(
                                  as_bf16x8(av), as_bf16x8(B[s]), accA, 0, 0, 0);
        }
    }

    #pragma unroll
    for (int r = 0; r < 16; ++r) accA[r] += accB[r];

    xs += __shfl_down(xs, 4, 8);
    xs += __shfl_down(xs, 2, 8);
    xs += __shfl_down(xs, 1, 8);
    if (iq == 0) s_xsp[g][ab] = xs;

    if (g == 1) {
        #pragma unroll
        for (int r = 0; r < 16; ++r) {
            int row = (r & 3) + ((r >> 2) << 3) + (h << 2);
            sbuf[row][n0 + am] = accA[r];
        }
    }
    __syncthreads();
    if (g == 0) {
        #pragma unroll
        for (int r = 0; r < 16; ++r) {
            int row = (r & 3) + ((r >> 2) << 3) + (h << 2);
            float v = accA[r] + sbuf[row][n0 + am] + s_xsp[0][row] + s_xsp[1][row];
            out[(b0 + row) * OUT + n0 + am] = v * (1.0f / 128.0f);
        }
    }
}

// ---------------- fallback (ws too small): R3's proven VALU kernel ----------------
__global__ __launch_bounds__(256, 2) void kan_valu(const float* __restrict__ x,
                                                   const float* __restrict__ cf,
                                                   float* __restrict__ out) {
    __shared__ float4        s_w[16][IN];
    __shared__ unsigned char s_m[16][IN];
    __shared__ float         s_xs[16];
    const int t = threadIdx.x;
    const int boff = blockIdx.x * 16;
    {
        const int b = t >> 4, il = t & 15;
        float xs = 0.f;
        #pragma unroll
        for (int k = 0; k < IN / 16; ++k) {
            int i = il + 16 * k;
            float xt = tanhf(x[(boff + b) * IN + i]);
            xs += xt;
            float s = (xt + 1.0f) * 7.5f;
            int m = (int)s; m = m < 0 ? 0 : (m > 14 ? 14 : m);
            float u = s - (float)m, om = 1.f - u, u2 = u * u;
            s_w[b][i] = make_float4((1.f/6.f)*om*om*om,
                                    (2.f/3.f) - u2*(1.f - 0.5f*u),
                                    (1.f/6.f) + 0.5f*(u + u2 - u2*u),
                                    (1.f/6.f)*u*u2);
            s_m[b][i] = (unsigned char)m;
        }
        for (int d = 8; d > 0; d >>= 1) xs += __shfl_down(xs, d, 16);
        if (il == 0) s_xs[b] = xs;
    }
    __syncthreads();
    const int w = t >> 6, l = t & 63;
    #pragma unroll
    for (int r = 0; r < 4; ++r) {
        const int b = w * 4 + r;
        float a0 = 0.f, a1 = 0.f;
        for (int i = 0; i < IN; ++i) {
            float4 wv = s_w[b][i];
            int m = (int)s_m[b][i];
            const float* p0 = cf + (2 * l) * ROW + i * NB + m;
            const float* p1 = p0 + ROW;
            a0 += wv.x * p0[0] + wv.y * p0[1] + wv.z * p0[2] + wv.w * p0[3];
            a1 += wv.x * p1[0] + wv.y * p1[1] + wv.z * p1[2] + wv.w * p1[3];
        }
        float xsv = s_xs[b];
        float2 st; st.x = (xsv + a0) / 128.f; st.y = (xsv + a1) / 128.f;
        ((float2*)out)[(boff + b) * (OUT / 2) + l] = st;
    }
}

extern "C" void kernel_launch(void* const* d_in, const int* in_sizes, int n_in,
                              void* d_out, int out_size, void* d_ws, size_t ws_size,
                              hipStream_t stream) {
    const float* x  = (const float*)d_in[0];
    const float* cf = (const float*)d_in[1];
    float* out = (float*)d_out;
    if (ws_size >= (size_t)CF_ELEMS * sizeof(unsigned short)) {
        unsigned short* cfb2 = (unsigned short*)d_ws;
        // Preferred: single fused cooperative launch (runtime validates co-residency).
        void* args[] = { (void*)&x, (void*)&cf, (void*)&cfb2, (void*)&out };
        hipError_t e = hipLaunchCooperativeKernel((const void*)kan_fused,
                                                  dim3(NBLK), dim3(512),
                                                  args, 0, stream);
        if (e != hipSuccess) {
            (void)hipGetLastError();   // clear error state
            // Proven two-kernel path (69.1 us baseline) — no hang possible.
            cvt_kernel<<<CF_ELEMS / 8 / 256, 256, 0, stream>>>(cf, cfb2);
            kan_mfma<<<BATCH / MT, 512, 0, stream>>>(x, cfb2, out);
        }
    } else {
        kan_valu<<<BATCH / 16, 256, 0, stream>>>(x, cf, out);
    }
}

// Round 3
// 68.795 us; speedup vs baseline: 2.5631x; 2.5631x over previous
//
#include <hip/hip_runtime.h>

#define BATCH 8192
#define IN 128
#define OUT 128
#define NB 18
#define ROW (IN * NB)          // 2304
#define CF_ELEMS (OUT * ROW)   // 294912
#define MT 32                  // batch rows per block
#define NCHG 4                 // K-chunks per K-group (2 groups x 4 x 288 = 2304)

typedef short  bf16x8 __attribute__((ext_vector_type(8)));
typedef float  f32x16 __attribute__((ext_vector_type(16)));

static __device__ __forceinline__ unsigned short f2bf(float f) {
    union { float f; unsigned u; } v; v.f = f;
    unsigned r = v.u + 0x7fffu + ((v.u >> 16) & 1u);   // RNE
    return (unsigned short)(r >> 16);
}
static __device__ __forceinline__ bf16x8 as_bf16x8(uint4 v) {
    union { uint4 u; bf16x8 b; } x; x.u = v; return x.b;
}
static __device__ __forceinline__ float fast_tanh(float v) {
    float e = __expf(2.0f * v);
    return 1.0f - 2.0f * __builtin_amdgcn_rcpf(e + 1.0f);
}

// cf fp32 [o][k] -> cfb2 bf16 tiled [k>>3][o][k&7]
__global__ __launch_bounds__(256) void cvt_kernel(const float* __restrict__ cf,
                                                  unsigned short* __restrict__ cfb2) {
    int tid = blockIdx.x * 256 + threadIdx.x;
    int o  = tid & 127;
    int kb = tid >> 7;
    const float4* src = (const float4*)(cf + o * ROW + kb * 8);
    float4 a = src[0], b = src[1];
    uint4 pk;
    pk.x = (unsigned)f2bf(a.x) | ((unsigned)f2bf(a.y) << 16);
    pk.y = (unsigned)f2bf(a.z) | ((unsigned)f2bf(a.w) << 16);
    pk.z = (unsigned)f2bf(b.x) | ((unsigned)f2bf(b.y) << 16);
    pk.w = (unsigned)f2bf(b.z) | ((unsigned)f2bf(b.w) << 16);
    ((uint4*)cfb2)[tid] = pk;
}

__global__ __launch_bounds__(512, 2) void kan_mfma(const float* __restrict__ x,
                                                   const unsigned short* __restrict__ cfb2,
                                                   float* __restrict__ out) {
    // A-tile transposed: [group][3 bufs][granule 0..35][row*4 + dw]
    __shared__ unsigned sAT[2][3][36][128];   // 108 KB
    __shared__ float sbuf[MT][132];           // 16.9 KB x-stage (132%32=4 -> conflict-free)
    __shared__ float s_xsp[2][MT];

    const int t  = threadIdx.x;
    const int g  = t >> 8;          // K-group 0/1
    const int tg = t & 255;
    const int w4 = (t >> 6) & 3;    // N-slice
    const int l  = t & 63;
    const int b0 = blockIdx.x * MT;
    const int n0 = w4 << 5;
    const int ab = tg >> 3;         // A-build row 0..31
    const int iq = tg & 7;
    const int h  = l >> 5;          // k-octet half
    const int am = l & 31;

    const uint4* bbase = (const uint4*)cfb2;
    const int o = n0 + am;

    // ---- B double-buffer: issue chunk c0's fragments FIRST (longest landing window) ----
    uint4 B[2][18];
    {
        const int c = g * NCHG;
        #pragma unroll
        for (int s = 0; s < 18; ++s)
            B[0][s] = bbase[(c * 36 + 2 * s + h) * 128 + o];
    }

    // ---- stage x (coalesced float4, 16B-aligned: 132*4B = 33*16B) ----
    {
        const float4* xp = (const float4*)(x + b0 * IN);
        int i0 = t;
        *(float4*)&sbuf[i0 >> 5][(i0 & 31) << 2] = xp[i0];
        int i1 = t + 512;
        *(float4*)&sbuf[i1 >> 5][(i1 & 31) << 2] = xp[i1];
    }
    __syncthreads();

    f32x16 accA, accB;
    #pragma unroll
    for (int r = 0; r < 16; ++r) { accA[r] = 0.f; accB[r] = 0.f; }
    float xs = 0.f;

    // ---- A-build for chunk c into buffer nb ----
    auto build = [&](int c, int nb) {
        unsigned* tile = &sAT[g][nb][0][0];
        #pragma unroll
        for (int hh = 0; hh < 2; ++hh) {
            int il = iq + (hh << 3);
            int i  = (c << 4) + il;
            float xt = fast_tanh(sbuf[ab][i]);
            xs += xt;
            float s = (xt + 1.0f) * 7.5f;
            int m = (int)s; m = m < 0 ? 0 : (m > 14 ? 14 : m);
            float u = s - (float)m, om = 1.f - u, u2 = u * u;
            float w0 = (1.f / 6.f) * om * om * om;
            float w1 = (2.f / 3.f) - u2 * (1.f - 0.5f * u);
            float w2 = (1.f / 6.f) + 0.5f * (u + u2 - u2 * u);
            float w3 = (1.f / 6.f) * u * u2;
            unsigned lo = (unsigned)f2bf(w0) | ((unsigned)f2bf(w1) << 16);
            unsigned hi = (unsigned)f2bf(w2) | ((unsigned)f2bf(w3) << 16);
            int odd = m & 1;
            unsigned t0 = odd ? (lo << 16) : lo;
            unsigned t1 = odd ? ((hi << 16) | (lo >> 16)) : hi;
            unsigned t2 = odd ? (hi >> 16) : 0u;
            int dq = m >> 1;
            int d0 = il * 9;
            #pragma unroll
            for (int j = 0; j < 9; ++j) {
                int d = d0 + j;
                unsigned v = (j == dq) ? t0 : (j == dq + 1) ? t1
                           : (j == dq + 2) ? t2 : 0u;
                tile[((d >> 2) << 7) + (ab << 2) + (d & 3)] = v;   // 2-way max
            }
        }
    };

    build(g * NCHG, 0);     // prologue: chunk 0 -> buf 0 (B[0] loads landing underneath)

    #pragma unroll
    for (int cc = 0; cc < NCHG; ++cc) {
        const int c = g * NCHG + cc;
        // issue NEXT chunk's B fragments: consumed only after build+sync+18 MFMAs
        if (cc + 1 < NCHG) {
            #pragma unroll
            for (int s = 0; s < 18; ++s)
                B[(cc + 1) & 1][s] = bbase[((c + 1) * 36 + 2 * s + h) * 128 + o];
            build(c + 1, (cc + 1) % 3);
        }
        __syncthreads();    // buf cc%3 complete for all waves
        const unsigned* tb = &sAT[g][cc % 3][0][0];
        #pragma unroll
        for (int s = 0; s < 18; ++s) {
            uint4 av = *(const uint4*)(tb + (((2 * s + h) << 7) + (am << 2)));
            if (s & 1) accB = __builtin_amdgcn_mfma_f32_32x32x16_bf16(
                                  as_bf16x8(av), as_bf16x8(B[cc & 1][s]), accB, 0, 0, 0);
            else       accA = __builtin_amdgcn_mfma_f32_32x32x16_bf16(
                                  as_bf16x8(av), as_bf16x8(B[cc & 1][s]), accA, 0, 0, 0);
        }
    }

    #pragma unroll
    for (int r = 0; r < 16; ++r) accA[r] += accB[r];

    // ---- tanh partial sums: 8 consecutive lanes share (g, ab) ----
    xs += __shfl_down(xs, 4, 8);
    xs += __shfl_down(xs, 2, 8);
    xs += __shfl_down(xs, 1, 8);
    if (iq == 0) s_xsp[g][ab] = xs;

    // ---- K-group reduction via sbuf (x-stage dead) ----
    if (g == 1) {
        #pragma unroll
        for (int r = 0; r < 16; ++r) {
            int row = (r & 3) + ((r >> 2) << 3) + (h << 2);
            sbuf[row][n0 + am] = accA[r];
        }
    }
    __syncthreads();
    if (g == 0) {
        #pragma unroll
        for (int r = 0; r < 16; ++r) {
            int row = (r & 3) + ((r >> 2) << 3) + (h << 2);
            float v = accA[r] + sbuf[row][n0 + am] + s_xsp[0][row] + s_xsp[1][row];
            out[(b0 + row) * OUT + n0 + am] = v * (1.0f / 128.0f);
        }
    }
}

// ---------------- fallback (ws too small): R3's proven VALU kernel ----------------
__global__ __launch_bounds__(256, 2) void kan_valu(const float* __restrict__ x,
                                                   const float* __restrict__ cf,
                                                   float* __restrict__ out) {
    __shared__ float4        s_w[16][IN];
    __shared__ unsigned char s_m[16][IN];
    __shared__ float         s_xs[16];
    const int t = threadIdx.x;
    const int boff = blockIdx.x * 16;
    {
        const int b = t >> 4, il = t & 15;
        float xs = 0.f;
        #pragma unroll
        for (int k = 0; k < IN / 16; ++k) {
            int i = il + 16 * k;
            float xt = tanhf(x[(boff + b) * IN + i]);
            xs += xt;
            float s = (xt + 1.0f) * 7.5f;
            int m = (int)s; m = m < 0 ? 0 : (m > 14 ? 14 : m);
            float u = s - (float)m, om = 1.f - u, u2 = u * u;
            s_w[b][i] = make_float4((1.f/6.f)*om*om*om,
                                    (2.f/3.f) - u2*(1.f - 0.5f*u),
                                    (1.f/6.f) + 0.5f*(u + u2 - u2*u),
                                    (1.f/6.f)*u*u2);
            s_m[b][i] = (unsigned char)m;
        }
        for (int d = 8; d > 0; d >>= 1) xs += __shfl_down(xs, d, 16);
        if (il == 0) s_xs[b] = xs;
    }
    __syncthreads();
    const int w = t >> 6, l = t & 63;
    #pragma unroll
    for (int r = 0; r < 4; ++r) {
        const int b = w * 4 + r;
        float a0 = 0.f, a1 = 0.f;
        for (int i = 0; i < IN; ++i) {
            float4 wv = s_w[b][i];
            int m = (int)s_m[b][i];
            const float* p0 = cf + (2 * l) * ROW + i * NB + m;
            const float* p1 = p0 + ROW;
            a0 += wv.x * p0[0] + wv.y * p0[1] + wv.z * p0[2] + wv.w * p0[3];
            a1 += wv.x * p1[0] + wv.y * p1[1] + wv.z * p1[2] + wv.w * p1[3];
        }
        float xsv = s_xs[b];
        float2 st; st.x = (xsv + a0) / 128.f; st.y = (xsv + a1) / 128.f;
        ((float2*)out)[(boff + b) * (OUT / 2) + l] = st;
    }
}

extern "C" void kernel_launch(void* const* d_in, const int* in_sizes, int n_in,
                              void* d_out, int out_size, void* d_ws, size_t ws_size,
                              hipStream_t stream) {
    const float* x  = (const float*)d_in[0];
    const float* cf = (const float*)d_in[1];
    float* out = (float*)d_out;
    if (ws_size >= (size_t)CF_ELEMS * sizeof(unsigned short)) {
        unsigned short* cfb2 = (unsigned short*)d_ws;
        cvt_kernel<<<CF_ELEMS / 8 / 256, 256, 0, stream>>>(cf, cfb2);
        kan_mfma<<<BATCH / MT, 512, 0, stream>>>(x, cfb2, out);
    } else {
        kan_valu<<<BATCH / 16, 256, 0, stream>>>(x, cf, out);
    }
}